// Round 8
// baseline (267.886 us; speedup 1.0000x reference)
//
#include <hip/hip_runtime.h>
#include <math.h>

#define Bsz 4
#define Tsz 2048
#define Csz 1024
#define NH  16
#define HD  64

typedef short bf16x8 __attribute__((ext_vector_type(8)));
typedef float f32x4  __attribute__((ext_vector_type(4)));
typedef unsigned short u16;
typedef unsigned int uint;

__device__ __forceinline__ u16 f2bf(float f) {
    union { float f; unsigned u; } v; v.f = f;
    unsigned r = v.u + 0x7fffu + ((v.u >> 16) & 1u);
    return (u16)(r >> 16);
}

__device__ __forceinline__ uint pkbf(float a, float b) {
    union { float f; uint u; } x, y; x.f = a; y.f = b;
    return ((x.u + 0x8000u) >> 16) | ((y.u + 0x8000u) & 0xFFFF0000u);
}

// async global->LDS, 16B per lane. LDS dest is wave-uniform base + lane*16B.
__device__ __forceinline__ void glds16(const u16* g, u16* l) {
    __builtin_amdgcn_global_load_lds(
        (const __attribute__((address_space(1))) void*)g,
        (__attribute__((address_space(3))) void*)l, 16, 0, 0);
}

// ---------------- fused cast (x + 4 weight matrices, one launch) ----------------
__global__ void cast_all(const float* __restrict__ x,
                         const float* __restrict__ s0, const float* __restrict__ s1,
                         const float* __restrict__ s2, const float* __restrict__ s3,
                         u16* __restrict__ xb, u16* __restrict__ wdst) {
    const int NW = Csz * Csz;
    const size_t NX = (size_t)Bsz * Tsz * Csz;
    size_t i = ((size_t)blockIdx.x * blockDim.x + threadIdx.x) * 8;
    const float* src;
    u16* dst;
    if (i < NX) {
        src = x + i; dst = xb + i;
    } else {
        size_t j = i - NX;
        int m = (int)(j >> 20);
        size_t local = j & (NW - 1);
        src = ((m == 0) ? s0 : (m == 1) ? s1 : (m == 2) ? s2 : s3) + local;
        dst = wdst + j;
    }
    float4 a = *(const float4*)(src);
    float4 b = *(const float4*)(src + 4);
    bf16x8 o;
    o[0] = (short)f2bf(a.x); o[1] = (short)f2bf(a.y);
    o[2] = (short)f2bf(a.z); o[3] = (short)f2bf(a.w);
    o[4] = (short)f2bf(b.x); o[5] = (short)f2bf(b.y);
    o[6] = (short)f2bf(b.z); o[7] = (short)f2bf(b.w);
    *(bf16x8*)(dst) = o;
}

// ================= 128x256 2-phase-per-K-tile GEMM template =================
// (unchanged from round 3/4 — see vmcnt ledger in history)

#define G2_SS 24576

#define G2_STAGEA(SLOT, KH, KT, PTR) {                                               \
    const int row_ = tid >> 2;                                                       \
    const int sc_ = (tid & 3) ^ ((row_ >> 1) & 3);                                   \
    glds16((PTR) + (size_t)row_ * 1024 + (KT) * 64 + (KH) * 32 + sc_ * 8,            \
           lds + (SLOT) * G2_SS + (KH) * 4096 + wave * 512); }

#define G2_STAGEB(SLOT, KH, KT, PTR) {                                               \
    _Pragma("unroll")                                                                \
    for (int rho = 0; rho < 2; rho++) {                                              \
        const int row_ = rho * 128 + (tid >> 2);                                     \
        const int sc_ = (tid & 3) ^ ((row_ >> 1) & 3);                               \
        glds16((PTR) + (size_t)row_ * 1024 + (KT) * 64 + (KH) * 32 + sc_ * 8,        \
               lds + (SLOT) * G2_SS + 8192 + (KH) * 8192 + rho * 4096 + wave * 512); } }

#define G2_PHASE(SLOT, KH, STAGE)                                                    \
    {                                                                                \
        __builtin_amdgcn_s_barrier();                                                \
        asm volatile("" ::: "memory");                                               \
        STAGE                                                                        \
        const u16* abase = lds + (SLOT) * G2_SS + (KH) * 4096;                       \
        const u16* bbase = lds + (SLOT) * G2_SS + 8192 + (KH) * 8192;                \
        bf16x8 afr[4], bfr[4];                                                       \
        _Pragma("unroll")                                                            \
        for (int i = 0; i < 4; i++) {                                                \
            const int ar = wrb + i * 16 + lr;                                        \
            afr[i] = *(const bf16x8*)(abase + ar * 32 +                              \
                                      ((lq ^ ((ar >> 1) & 3)) * 8));                 \
        }                                                                            \
        _Pragma("unroll")                                                            \
        for (int j = 0; j < 4; j++) {                                                \
            const int nr = wcb + j * 16 + lr;                                        \
            bfr[j] = *(const bf16x8*)(bbase + nr * 32 +                              \
                                      ((lq ^ ((nr >> 1) & 3)) * 8));                 \
        }                                                                            \
        asm volatile("" ::: "memory");                                               \
        __builtin_amdgcn_s_setprio(1);                                               \
        _Pragma("unroll")                                                            \
        for (int i = 0; i < 4; i++)                                                  \
            _Pragma("unroll")                                                        \
            for (int j = 0; j < 4; j++)                                              \
                acc[i][j] = __builtin_amdgcn_mfma_f32_16x16x32_bf16(                 \
                    afr[i], bfr[j], acc[i][j], 0, 0, 0);                             \
        __builtin_amdgcn_s_setprio(0);                                               \
    }

#define G2_VM(N) asm volatile("s_waitcnt vmcnt(" #N ")" ::: "memory")

#define G2_BODY(AP_, BP_)                                                            \
    __shared__ u16 lds[49152];                                                       \
    const int tid = threadIdx.x;                                                     \
    const int wave = tid >> 6, lane = tid & 63;                                      \
    const int lr = lane & 15, lq = lane >> 4;                                        \
    const int wrb = (wave >> 2) * 64, wcb = (wave & 3) * 64;                         \
    f32x4 acc[4][4] = {};                                                            \
    G2_STAGEA(0, 0, 0, AP_) G2_STAGEB(0, 0, 0, BP_)                                  \
    G2_STAGEA(0, 1, 0, AP_) G2_STAGEB(0, 1, 0, BP_)                                  \
    G2_STAGEA(1, 0, 1, AP_) G2_STAGEB(1, 0, 1, BP_)                                  \
    for (int t = 0; t < 16; t++) {                                                   \
        const int s = t & 1;                                                         \
        if (t == 15) { G2_VM(3); } else { G2_VM(6); }                                \
        G2_PHASE(s, 0, if (t < 15) { G2_STAGEA(s ^ 1, 1, t + 1, AP_)                 \
                                     G2_STAGEB(s ^ 1, 1, t + 1, BP_) })              \
        if (t == 15) { G2_VM(0); } else { G2_VM(6); }                                \
        G2_PHASE(s, 1, if (t < 14) { G2_STAGEA(s, 0, t + 2, AP_)                     \
                                     G2_STAGEB(s, 0, t + 2, BP_) })                  \
    }

// ---------------- fused QKV GEMM ----------------
__global__ __launch_bounds__(512, 2)
void gemm_qkv(const u16* __restrict__ A, const u16* __restrict__ Bm,
              u16* __restrict__ Qo, u16* __restrict__ Ko, u16* __restrict__ Vo,
              float qscale) {
    const int wg = blockIdx.x;
    const int chunk = wg & 7, pos = wg >> 3;            // chunk = XCD, pos 0..95
    const int m0 = ((chunk >> 1) * 16 + pos / 6) * 128;
    const int n0 = ((chunk & 1) * 6 + pos % 6) * 256;
    const u16* Ap = A  + (size_t)m0 * 1024;
    const u16* Bp = Bm + (size_t)n0 * 1024;

    G2_BODY(Ap, Bp)

    const int sel = n0 >> 10;   // block-uniform: 0=Q, 1=K, 2=V
    if (sel == 2) {
        #pragma unroll
        for (int mi = 0; mi < 4; mi++) {
            #pragma unroll
            for (int ni = 0; ni < 4; ni++) {
                int m = m0 + wrb + mi * 16 + lq * 4;
                int b = m >> 11, tt = m & (Tsz - 1);
                int n = (n0 & 1023) + wcb + ni * 16 + lr;
                int h = n >> 6, d = n & (HD - 1);
                uint2 pk;
                pk.x = pkbf(acc[mi][ni][0], acc[mi][ni][1]);
                pk.y = pkbf(acc[mi][ni][2], acc[mi][ni][3]);
                *(uint2*)(&Vo[(((size_t)b * NH + h) * HD + d) * Tsz + tt]) = pk;
            }
        }
    } else {
        const float scale = (sel == 0) ? qscale : 1.0f;
        u16* dst = (sel == 0) ? Qo : Ko;
        #pragma unroll
        for (int mi = 0; mi < 4; mi++)
            #pragma unroll
            for (int ni = 0; ni < 4; ni++)
                #pragma unroll
                for (int r = 0; r < 4; r++) {
                    int m = m0 + wrb + mi * 16 + lq * 4 + r;
                    int n = (n0 & 1023) + wcb + ni * 16 + lr;
                    int b = m >> 11, tt = m & (Tsz - 1);
                    int h = n >> 6,  d = n & (HD - 1);
                    dst[(((size_t)b * NH + h) * Tsz + tt) * HD + d] = f2bf(acc[mi][ni][r] * scale);
                }
    }
}

// ---------------- output projection GEMM ----------------
__global__ __launch_bounds__(512, 2)
void gemm_out(const u16* __restrict__ A, const u16* __restrict__ Bm,
              float* __restrict__ out) {
    const int wg = blockIdx.x;
    const int chunk = wg & 7, pos = wg >> 3;            // pos 0..31
    const int m0 = (chunk * 8 + (pos >> 2)) * 128;
    const int n0 = (pos & 3) * 256;
    const u16* Ap = A  + (size_t)m0 * 1024;
    const u16* Bp = Bm + (size_t)n0 * 1024;

    G2_BODY(Ap, Bp)

    #pragma unroll
    for (int mi = 0; mi < 4; mi++)
        #pragma unroll
        for (int ni = 0; ni < 4; ni++)
            #pragma unroll
            for (int r = 0; r < 4; r++) {
                int m = m0 + wrb + mi * 16 + lq * 4 + r;
                int n = n0 + wcb + ni * 16 + lr;
                out[(size_t)m * Csz + n] = acc[mi][ni][r];
            }
}

// ---------------- flash attention ----------------
// Round-8 changes (on the unpaired round-7 structure, which matched round-4's
// 77 us with lower VGPR):
//  1) Swapped QK^T: accS = mfma(K_frag, Q_frag) = S^T fragment. Lane then
//     holds k = j*16+lq*4+r (contiguous in r) for q = lr, so the 4 exp
//     results per j pack into one uint2 -> sP write is 4x ds_write_b64
//     instead of 16x ds_write_u16. sP layout stays [q][k]; row = lr; the PV
//     read side (pf at row lr) is byte-identical. A/B frag symmetry of
//     mfma_16x16x32 makes the swap legal (GEMM loads both identically).
//  2) Diagonal iteration peeled: main loop has no mask code (the 16
//     cmp+cndmask run only in the single masked epilogue). Exactly 2 body
//     instantiations (round-3's 6x I-cache blowup avoided).
#define LDT  72
#define LDTP 68

__global__ __launch_bounds__(256, 4)
void attn_kernel(const u16* __restrict__ Q, const u16* __restrict__ Kb,
                 const u16* __restrict__ Vt, u16* __restrict__ O) {
    __shared__ u16 sK[64 * LDT];
    __shared__ u16 sV[64 * LDT];
    __shared__ u16 sP[4][16 * LDTP];
    const int tid  = threadIdx.x;
    const int wave = tid >> 6, lane = tid & 63;
    const int lr = lane & 15, lq = lane >> 4;
    const int bh = blockIdx.x;           // 0..63  (XCD swizzle: id%8 == bh%8)
    const int tq = 31 - blockIdx.y;      // q-tile index; longest first (LPT)
    const int tc = tq * 64;

    const u16* Qp = Q  + (size_t)bh * Tsz * HD;
    const u16* Kp = Kb + (size_t)bh * Tsz * HD;
    const u16* Vp = Vt + (size_t)bh * HD * Tsz;

    bf16x8 qf0 = *(const bf16x8*)(Qp + (size_t)(tc + wave * 16 + lr) * HD + lq * 8);
    bf16x8 qf1 = *(const bf16x8*)(Qp + (size_t)(tc + wave * 16 + lr) * HD + 32 + lq * 8);

    f32x4 accO[4] = {};
    f32x4 accL = {};

    bf16x8 ones;
    #pragma unroll
    for (int i = 0; i < 8; i++) ones[i] = (short)0x3F80;  // bf16 1.0

    const int strow = tid >> 3;
    const int stcol = (tid & 7) * 8;
    const u16* gK0 = Kp + (size_t)strow * HD + stcol;
    const u16* gK1 = gK0 + 32 * HD;
    const u16* gV0 = Vp + (size_t)strow * Tsz + stcol;
    const u16* gV1 = gV0 + 32 * Tsz;
    u16* lK0 = sK + strow * LDT + stcol;  u16* lK1 = lK0 + 32 * LDT;
    u16* lV0 = sV + strow * LDT + stcol;  u16* lV1 = lV0 + 32 * LDT;

    bf16x8 pK0 = *(const bf16x8*)(gK0);
    bf16x8 pK1 = *(const bf16x8*)(gK1);
    bf16x8 pV0 = *(const bf16x8*)(gV0);
    bf16x8 pV1 = *(const bf16x8*)(gV1);

    u16* sPw = &sP[wave][0];

    // QK^T (swapped) + softmax-exp + PV for the tile currently in LDS.
    // MASKED=0: no causal mask code at all.
#define PROCESS_BODY(MASKED)                                                          \
    {                                                                                 \
        f32x4 accS[4];                                                                \
        _Pragma("unroll")                                                             \
        for (int j = 0; j < 4; j++) {                                                 \
            bf16x8 b0 = *(const bf16x8*)(sK + (j * 16 + lr) * LDT + lq * 8);          \
            bf16x8 b1 = *(const bf16x8*)(sK + (j * 16 + lr) * LDT + 32 + lq * 8);     \
            f32x4 z = {};                                                             \
            z = __builtin_amdgcn_mfma_f32_16x16x32_bf16(b0, qf0, z, 0, 0, 0);         \
            z = __builtin_amdgcn_mfma_f32_16x16x32_bf16(b1, qf1, z, 0, 0, 0);         \
            accS[j] = z;                                                              \
        }                                                                             \
        _Pragma("unroll")                                                             \
        for (int j = 0; j < 4; j++) {                                                 \
            uint2 pk;                                                                 \
            union { float f; uint u; } e0, e1, e2, e3;                                \
            float v0 = accS[j][0], v1 = accS[j][1];                                   \
            float v2 = accS[j][2], v3 = accS[j][3];                                   \
            if (MASKED) {                                                             \
                const int qrow = wave * 16 + lr;                                      \
                const int kcol = j * 16 + lq * 4;                                     \
                if (kcol + 0 > qrow) v0 = -200.0f;                                    \
                if (kcol + 1 > qrow) v1 = -200.0f;                                    \
                if (kcol + 2 > qrow) v2 = -200.0f;                                    \
                if (kcol + 3 > qrow) v3 = -200.0f;                                    \
            }                                                                         \
            e0.f = __builtin_amdgcn_exp2f(v0);                                        \
            e1.f = __builtin_amdgcn_exp2f(v1);                                        \
            e2.f = __builtin_amdgcn_exp2f(v2);                                        \
            e3.f = __builtin_amdgcn_exp2f(v3);                                        \
            pk.x = (e0.u >> 16) | (e1.u & 0xFFFF0000u);                               \
            pk.y = (e2.u >> 16) | (e3.u & 0xFFFF0000u);                               \
            *(uint2*)(sPw + lr * LDTP + j * 16 + lq * 4) = pk;                        \
        }                                                                             \
        _Pragma("unroll")                                                             \
        for (int ks = 0; ks < 2; ks++) {                                              \
            bf16x8 pf = *(const bf16x8*)(sPw + lr * LDTP + ks * 32 + lq * 8);         \
            accL = __builtin_amdgcn_mfma_f32_16x16x32_bf16(pf, ones, accL, 0, 0, 0);  \
            _Pragma("unroll")                                                         \
            for (int j = 0; j < 4; j++) {                                             \
                bf16x8 vf = *(const bf16x8*)(sV + (j * 16 + lr) * LDT + ks * 32 + lq * 8); \
                accO[j] = __builtin_amdgcn_mfma_f32_16x16x32_bf16(pf, vf, accO[j], 0, 0, 0); \
            }                                                                         \
        }                                                                             \
    }

    for (int kb = 0; kb < tq; kb++) {
        __syncthreads();   // previous iteration's LDS reads complete
        *(bf16x8*)lK0 = pK0; *(bf16x8*)lK1 = pK1;
        *(bf16x8*)lV0 = pV0; *(bf16x8*)lV1 = pV1;
        __syncthreads();
        pK0 = *(const bf16x8*)(gK0 + (size_t)(kb + 1) * 64 * HD);
        pK1 = *(const bf16x8*)(gK1 + (size_t)(kb + 1) * 64 * HD);
        pV0 = *(const bf16x8*)(gV0 + (kb + 1) * 64);
        pV1 = *(const bf16x8*)(gV1 + (kb + 1) * 64);
        PROCESS_BODY(0)
    }
    // diagonal epilogue (kb == tq): only place with mask code
    __syncthreads();
    *(bf16x8*)lK0 = pK0; *(bf16x8*)lK1 = pK1;
    *(bf16x8*)lV0 = pV0; *(bf16x8*)lV1 = pV1;
    __syncthreads();
    PROCESS_BODY(1)
#undef PROCESS_BODY

    const int b = bh >> 4, h = bh & 15;
    #pragma unroll
    for (int j = 0; j < 4; j++) {
        #pragma unroll
        for (int r = 0; r < 4; r++) {
            int t = wave * 16 + lq * 4 + r;
            int d = j * 16 + lr;
            O[((size_t)b * Tsz + tc + t) * Csz + h * HD + d] = f2bf(accO[j][r] / accL[r]);
        }
    }
}

// ---------------- launcher ----------------
extern "C" void kernel_launch(void* const* d_in, const int* in_sizes, int n_in,
                              void* d_out, int out_size, void* d_ws, size_t ws_size,
                              hipStream_t stream) {
    const float* x  = (const float*)d_in[0];
    const float* Wq = (const float*)d_in[1];
    const float* Wk = (const float*)d_in[2];
    const float* Wv = (const float*)d_in[3];
    const float* Wo = (const float*)d_in[4];
    float* out = (float*)d_out;

    const size_t NX = (size_t)Bsz * Tsz * Csz;  // 8388608
    const size_t NW = (size_t)Csz * Csz;        // 1048576

    char* ws = (char*)d_ws;
    u16* xb   = (u16*)ws; ws += NX * 2;
    u16* wqkv = (u16*)ws; ws += 3 * NW * 2;
    u16* wob  = (u16*)ws; ws += NW * 2;         // contiguous after wqkv (cast target)
    u16* qbuf = (u16*)ws; ws += NX * 2;
    u16* kbuf = (u16*)ws; ws += NX * 2;
    u16* vtb  = (u16*)ws; ws += NX * 2;
    u16* abuf = (u16*)ws; ws += NX * 2;

    cast_all<<<dim3((unsigned)((NX + 4 * NW) / 2048)), 256, 0, stream>>>(
        x, Wq, Wk, Wv, Wo, xb, wqkv);

    const float qscale = 0.125f * 1.44269504088896340736f;  // 1/sqrt(64) * log2(e)
    gemm_qkv<<<dim3(768), 512, 0, stream>>>(xb, wqkv, qbuf, kbuf, vtb, qscale);

    attn_kernel<<<dim3(Bsz * NH, 32), 256, 0, stream>>>(qbuf, kbuf, vtb, abuf);

    gemm_out<<<dim3(256), 512, 0, stream>>>(abuf, wob, out);
}

// Round 9
// 247.921 us; speedup vs baseline: 1.0805x; 1.0805x over previous
//
#include <hip/hip_runtime.h>
#include <math.h>

#define Bsz 4
#define Tsz 2048
#define Csz 1024
#define NH  16
#define HD  64

typedef short bf16x8 __attribute__((ext_vector_type(8)));
typedef float f32x4  __attribute__((ext_vector_type(4)));
typedef unsigned short u16;
typedef unsigned int uint;

__device__ __forceinline__ u16 f2bf(float f) {
    union { float f; unsigned u; } v; v.f = f;
    unsigned r = v.u + 0x7fffu + ((v.u >> 16) & 1u);
    return (u16)(r >> 16);
}

__device__ __forceinline__ uint pkbf(float a, float b) {
    union { float f; uint u; } x, y; x.f = a; y.f = b;
    return ((x.u + 0x8000u) >> 16) | ((y.u + 0x8000u) & 0xFFFF0000u);
}

// async global->LDS, 16B per lane. LDS dest is wave-uniform base + lane*16B.
__device__ __forceinline__ void glds16(const u16* g, u16* l) {
    __builtin_amdgcn_global_load_lds(
        (const __attribute__((address_space(1))) void*)g,
        (__attribute__((address_space(3))) void*)l, 16, 0, 0);
}

// ---------------- fused cast (x + 4 weight matrices, one launch) ----------------
// NX/8 elements-per-thread boundary = 1048576 = block 4096 exactly, so the
// source-select branch is block-uniform.
__global__ void cast_all(const float* __restrict__ x,
                         const float* __restrict__ s0, const float* __restrict__ s1,
                         const float* __restrict__ s2, const float* __restrict__ s3,
                         u16* __restrict__ xb, u16* __restrict__ wdst) {
    const int NW = Csz * Csz;
    const size_t NX = (size_t)Bsz * Tsz * Csz;
    size_t i = ((size_t)blockIdx.x * blockDim.x + threadIdx.x) * 8;
    const float* src;
    u16* dst;
    if (i < NX) {
        src = x + i; dst = xb + i;
    } else {
        size_t j = i - NX;
        int m = (int)(j >> 20);
        size_t local = j & (NW - 1);
        src = ((m == 0) ? s0 : (m == 1) ? s1 : (m == 2) ? s2 : s3) + local;
        dst = wdst + j;
    }
    float4 a = *(const float4*)(src);
    float4 b = *(const float4*)(src + 4);
    bf16x8 o;
    o[0] = (short)f2bf(a.x); o[1] = (short)f2bf(a.y);
    o[2] = (short)f2bf(a.z); o[3] = (short)f2bf(a.w);
    o[4] = (short)f2bf(b.x); o[5] = (short)f2bf(b.y);
    o[6] = (short)f2bf(b.z); o[7] = (short)f2bf(b.w);
    *(bf16x8*)(dst) = o;
}

// ================= 128x256 2-phase-per-K-tile GEMM template =================
// BM=128, BN=256, BK=64 (two k-halves of 32). 512 threads = 8 waves (2Mx4N),
// wave tile 64x64 = acc[4][4]. Per phase: read 4 A-frags + 4 B-frags, 16 MFMA.
// LDS: slot = A(16KB) + B(32KB) = 48KB; 2 slots = 96KB -> 1 block/CU.
//
// vmcnt ledger: see round-3/4 history. Steady state vmcnt(6); tail {3,0}.
// Bank swizzle: 16B chunk c of row r stored at c^((r>>1)&3), applied on the
// glds GLOBAL source (LDS dest linear) and XOR'd on the ds_read side.

#define G2_SS 24576

#define G2_STAGEA(SLOT, KH, KT, PTR) {                                               \
    const int row_ = tid >> 2;                                                       \
    const int sc_ = (tid & 3) ^ ((row_ >> 1) & 3);                                   \
    glds16((PTR) + (size_t)row_ * 1024 + (KT) * 64 + (KH) * 32 + sc_ * 8,            \
           lds + (SLOT) * G2_SS + (KH) * 4096 + wave * 512); }

#define G2_STAGEB(SLOT, KH, KT, PTR) {                                               \
    _Pragma("unroll")                                                                \
    for (int rho = 0; rho < 2; rho++) {                                              \
        const int row_ = rho * 128 + (tid >> 2);                                     \
        const int sc_ = (tid & 3) ^ ((row_ >> 1) & 3);                               \
        glds16((PTR) + (size_t)row_ * 1024 + (KT) * 64 + (KH) * 32 + sc_ * 8,        \
               lds + (SLOT) * G2_SS + 8192 + (KH) * 8192 + rho * 4096 + wave * 512); } }

#define G2_PHASE(SLOT, KH, STAGE)                                                    \
    {                                                                                \
        __builtin_amdgcn_s_barrier();                                                \
        asm volatile("" ::: "memory");                                               \
        STAGE                                                                        \
        const u16* abase = lds + (SLOT) * G2_SS + (KH) * 4096;                       \
        const u16* bbase = lds + (SLOT) * G2_SS + 8192 + (KH) * 8192;                \
        bf16x8 afr[4], bfr[4];                                                       \
        _Pragma("unroll")                                                            \
        for (int i = 0; i < 4; i++) {                                                \
            const int ar = wrb + i * 16 + lr;                                        \
            afr[i] = *(const bf16x8*)(abase + ar * 32 +                              \
                                      ((lq ^ ((ar >> 1) & 3)) * 8));                 \
        }                                                                            \
        _Pragma("unroll")                                                            \
        for (int j = 0; j < 4; j++) {                                                \
            const int nr = wcb + j * 16 + lr;                                        \
            bfr[j] = *(const bf16x8*)(bbase + nr * 32 +                              \
                                      ((lq ^ ((nr >> 1) & 3)) * 8));                 \
        }                                                                            \
        asm volatile("" ::: "memory");                                               \
        __builtin_amdgcn_s_setprio(1);                                               \
        _Pragma("unroll")                                                            \
        for (int i = 0; i < 4; i++)                                                  \
            _Pragma("unroll")                                                        \
            for (int j = 0; j < 4; j++)                                              \
                acc[i][j] = __builtin_amdgcn_mfma_f32_16x16x32_bf16(                 \
                    afr[i], bfr[j], acc[i][j], 0, 0, 0);                             \
        __builtin_amdgcn_s_setprio(0);                                               \
    }

#define G2_VM(N) asm volatile("s_waitcnt vmcnt(" #N ")" ::: "memory")

#define G2_BODY(AP_, BP_)                                                            \
    __shared__ u16 lds[49152];                                                       \
    const int tid = threadIdx.x;                                                     \
    const int wave = tid >> 6, lane = tid & 63;                                      \
    const int lr = lane & 15, lq = lane >> 4;                                        \
    const int wrb = (wave >> 2) * 64, wcb = (wave & 3) * 64;                         \
    f32x4 acc[4][4] = {};                                                            \
    G2_STAGEA(0, 0, 0, AP_) G2_STAGEB(0, 0, 0, BP_)                                  \
    G2_STAGEA(0, 1, 0, AP_) G2_STAGEB(0, 1, 0, BP_)                                  \
    G2_STAGEA(1, 0, 1, AP_) G2_STAGEB(1, 0, 1, BP_)                                  \
    for (int t = 0; t < 16; t++) {                                                   \
        const int s = t & 1;                                                         \
        if (t == 15) { G2_VM(3); } else { G2_VM(6); }                                \
        G2_PHASE(s, 0, if (t < 15) { G2_STAGEA(s ^ 1, 1, t + 1, AP_)                 \
                                     G2_STAGEB(s ^ 1, 1, t + 1, BP_) })              \
        if (t == 15) { G2_VM(0); } else { G2_VM(6); }                                \
        G2_PHASE(s, 1, if (t < 14) { G2_STAGEA(s, 0, t + 2, AP_)                     \
                                     G2_STAGEB(s, 0, t + 2, BP_) })                  \
    }

// ---------------- fused QKV GEMM ----------------
// Grid: 768 flat blocks (64 m-tiles x 12 n-tiles) = 3 FULL dispatch rounds at
// 1 block/CU (no tail). XCD-chunked (768%8==0, bijective).
__global__ __launch_bounds__(512, 2)
void gemm_qkv(const u16* __restrict__ A, const u16* __restrict__ Bm,
              u16* __restrict__ Qo, u16* __restrict__ Ko, u16* __restrict__ Vo,
              float qscale) {
    const int wg = blockIdx.x;
    const int chunk = wg & 7, pos = wg >> 3;            // chunk = XCD, pos 0..95
    const int m0 = ((chunk >> 1) * 16 + pos / 6) * 128;
    const int n0 = ((chunk & 1) * 6 + pos % 6) * 256;
    const u16* Ap = A  + (size_t)m0 * 1024;
    const u16* Bp = Bm + (size_t)n0 * 1024;

    G2_BODY(Ap, Bp)

    const int sel = n0 >> 10;   // block-uniform: 0=Q, 1=K, 2=V
    if (sel == 2) {
        #pragma unroll
        for (int mi = 0; mi < 4; mi++) {
            #pragma unroll
            for (int ni = 0; ni < 4; ni++) {
                int m = m0 + wrb + mi * 16 + lq * 4;
                int b = m >> 11, tt = m & (Tsz - 1);
                int n = (n0 & 1023) + wcb + ni * 16 + lr;
                int h = n >> 6, d = n & (HD - 1);
                uint2 pk;
                pk.x = pkbf(acc[mi][ni][0], acc[mi][ni][1]);
                pk.y = pkbf(acc[mi][ni][2], acc[mi][ni][3]);
                *(uint2*)(&Vo[(((size_t)b * NH + h) * HD + d) * Tsz + tt]) = pk;
            }
        }
    } else {
        const float scale = (sel == 0) ? qscale : 1.0f;
        u16* dst = (sel == 0) ? Qo : Ko;
        #pragma unroll
        for (int mi = 0; mi < 4; mi++)
            #pragma unroll
            for (int ni = 0; ni < 4; ni++)
                #pragma unroll
                for (int r = 0; r < 4; r++) {
                    int m = m0 + wrb + mi * 16 + lq * 4 + r;
                    int n = (n0 & 1023) + wcb + ni * 16 + lr;
                    int b = m >> 11, tt = m & (Tsz - 1);
                    int h = n >> 6,  d = n & (HD - 1);
                    dst[(((size_t)b * NH + h) * Tsz + tt) * HD + d] = f2bf(acc[mi][ni][r] * scale);
                }
    }
}

// ---------------- output projection GEMM ----------------
// Grid: 256 blocks (64 m-tiles x 4 n-tiles) = exactly 1 full round.
__global__ __launch_bounds__(512, 2)
void gemm_out(const u16* __restrict__ A, const u16* __restrict__ Bm,
              float* __restrict__ out) {
    const int wg = blockIdx.x;
    const int chunk = wg & 7, pos = wg >> 3;            // pos 0..31
    const int m0 = (chunk * 8 + (pos >> 2)) * 128;
    const int n0 = (pos & 3) * 256;
    const u16* Ap = A  + (size_t)m0 * 1024;
    const u16* Bp = Bm + (size_t)n0 * 1024;

    G2_BODY(Ap, Bp)

    #pragma unroll
    for (int mi = 0; mi < 4; mi++)
        #pragma unroll
        for (int ni = 0; ni < 4; ni++)
            #pragma unroll
            for (int r = 0; r < 4; r++) {
                int m = m0 + wrb + mi * 16 + lq * 4 + r;
                int n = n0 + wcb + ni * 16 + lr;
                out[(size_t)m * Csz + n] = acc[mi][ni][r];
            }
}

// ---------------- flash attention (round-7 fixed point, exact) ----------------
// Unpaired q-tiles (2048 blocks, LPT order), VGPR 56, 27.1KB LDS, 77.4 us.
// FAILED perturbation log (do not repeat):
//  r3: compile-time DIAG 6x instantiation + setprio  -> 77->88 (I-cache, m190 regime)
//  r5: KVBLK=128                                      -> 77->87 (occupancy 34->25)
//  r8: swapped QK^T + packed b64 sP-write + peel      -> 77->90 (sP write 4-way
//      bank conflict at 2(lr+lq) mod 32 + 4-exp2 pack dependency on the
//      softmax critical path; MfmaUtil 21.5->17.5)
// Structure is a co-designed local optimum; exit requires the full 8-wave
// 32x32 in-register-softmax rewrite, not local edits.
#define LDT  72
#define LDTP 68

__global__ __launch_bounds__(256, 4)
void attn_kernel(const u16* __restrict__ Q, const u16* __restrict__ Kb,
                 const u16* __restrict__ Vt, u16* __restrict__ O) {
    __shared__ u16 sK[64 * LDT];
    __shared__ u16 sV[64 * LDT];
    __shared__ u16 sP[4][16 * LDTP];
    const int tid  = threadIdx.x;
    const int wave = tid >> 6, lane = tid & 63;
    const int lr = lane & 15, lq = lane >> 4;
    const int bh = blockIdx.x;           // 0..63  (XCD swizzle: id%8 == bh%8)
    const int tq = 31 - blockIdx.y;      // q-tile index; longest first (LPT)
    const int tc = tq * 64;

    const u16* Qp = Q  + (size_t)bh * Tsz * HD;
    const u16* Kp = Kb + (size_t)bh * Tsz * HD;
    const u16* Vp = Vt + (size_t)bh * HD * Tsz;

    bf16x8 qf0 = *(const bf16x8*)(Qp + (size_t)(tc + wave * 16 + lr) * HD + lq * 8);
    bf16x8 qf1 = *(const bf16x8*)(Qp + (size_t)(tc + wave * 16 + lr) * HD + 32 + lq * 8);

    f32x4 accO[4] = {};
    f32x4 accL = {};

    bf16x8 ones;
    #pragma unroll
    for (int i = 0; i < 8; i++) ones[i] = (short)0x3F80;  // bf16 1.0

    const int strow = tid >> 3;
    const int stcol = (tid & 7) * 8;
    const u16* gK0 = Kp + (size_t)strow * HD + stcol;
    const u16* gK1 = gK0 + 32 * HD;
    const u16* gV0 = Vp + (size_t)strow * Tsz + stcol;
    const u16* gV1 = gV0 + 32 * Tsz;
    u16* lK0 = sK + strow * LDT + stcol;  u16* lK1 = lK0 + 32 * LDT;
    u16* lV0 = sV + strow * LDT + stcol;  u16* lV1 = lV0 + 32 * LDT;

    bf16x8 pK0 = *(const bf16x8*)(gK0);
    bf16x8 pK1 = *(const bf16x8*)(gK1);
    bf16x8 pV0 = *(const bf16x8*)(gV0);
    bf16x8 pV1 = *(const bf16x8*)(gV1);

    for (int kb = 0; kb <= tq; kb++) {
        __syncthreads();   // previous iteration's LDS reads complete
        *(bf16x8*)lK0 = pK0; *(bf16x8*)lK1 = pK1;
        *(bf16x8*)lV0 = pV0; *(bf16x8*)lV1 = pV1;
        __syncthreads();
        if (kb < tq) {
            pK0 = *(const bf16x8*)(gK0 + (size_t)(kb + 1) * 64 * HD);
            pK1 = *(const bf16x8*)(gK1 + (size_t)(kb + 1) * 64 * HD);
            pV0 = *(const bf16x8*)(gV0 + (kb + 1) * 64);
            pV1 = *(const bf16x8*)(gV1 + (kb + 1) * 64);
        }
        {
            const int DIAG = (kb == tq);
            f32x4 accS[4];
            #pragma unroll
            for (int j = 0; j < 4; j++) {
                bf16x8 b0 = *(const bf16x8*)(sK + (j * 16 + lr) * LDT + lq * 8);
                bf16x8 b1 = *(const bf16x8*)(sK + (j * 16 + lr) * LDT + 32 + lq * 8);
                f32x4 z = {};
                z = __builtin_amdgcn_mfma_f32_16x16x32_bf16(qf0, b0, z, 0, 0, 0);
                z = __builtin_amdgcn_mfma_f32_16x16x32_bf16(qf1, b1, z, 0, 0, 0);
                accS[j] = z;
            }
            #pragma unroll
            for (int r = 0; r < 4; r++) {
                const int rowg = tc + wave * 16 + lq * 4 + r;
                #pragma unroll
                for (int j = 0; j < 4; j++) {
                    float v = accS[j][r];
                    if (DIAG && (kb * 64 + j * 16 + lr > rowg)) v = -200.0f;
                    union { float f; uint u; } e;
                    e.f = __builtin_amdgcn_exp2f(v);
                    sP[wave][(lq * 4 + r) * LDTP + j * 16 + lr] = (u16)(e.u >> 16);
                }
            }
            #pragma unroll
            for (int ks = 0; ks < 2; ks++) {
                bf16x8 pf = *(const bf16x8*)(&sP[wave][0] + lr * LDTP + ks * 32 + lq * 8);
                accL = __builtin_amdgcn_mfma_f32_16x16x32_bf16(pf, ones, accL, 0, 0, 0);
                #pragma unroll
                for (int j = 0; j < 4; j++) {
                    bf16x8 vf = *(const bf16x8*)(sV + (j * 16 + lr) * LDT + ks * 32 + lq * 8);
                    accO[j] = __builtin_amdgcn_mfma_f32_16x16x32_bf16(pf, vf, accO[j], 0, 0, 0);
                }
            }
        }
    }

    const int b = bh >> 4, h = bh & 15;
    #pragma unroll
    for (int j = 0; j < 4; j++) {
        #pragma unroll
        for (int r = 0; r < 4; r++) {
            int t = wave * 16 + lq * 4 + r;
            int d = j * 16 + lr;
            O[((size_t)b * Tsz + tc + t) * Csz + h * HD + d] = f2bf(accO[j][r] / accL[r]);
        }
    }
}

// ---------------- launcher ----------------
extern "C" void kernel_launch(void* const* d_in, const int* in_sizes, int n_in,
                              void* d_out, int out_size, void* d_ws, size_t ws_size,
                              hipStream_t stream) {
    const float* x  = (const float*)d_in[0];
    const float* Wq = (const float*)d_in[1];
    const float* Wk = (const float*)d_in[2];
    const float* Wv = (const float*)d_in[3];
    const float* Wo = (const float*)d_in[4];
    float* out = (float*)d_out;

    const size_t NX = (size_t)Bsz * Tsz * Csz;  // 8388608
    const size_t NW = (size_t)Csz * Csz;        // 1048576

    char* ws = (char*)d_ws;
    u16* xb   = (u16*)ws; ws += NX * 2;
    u16* wqkv = (u16*)ws; ws += 3 * NW * 2;
    u16* wob  = (u16*)ws; ws += NW * 2;         // contiguous after wqkv (cast target)
    u16* qbuf = (u16*)ws; ws += NX * 2;
    u16* kbuf = (u16*)ws; ws += NX * 2;
    u16* vtb  = (u16*)ws; ws += NX * 2;
    u16* abuf = (u16*)ws; ws += NX * 2;

    cast_all<<<dim3((unsigned)((NX + 4 * NW) / 2048)), 256, 0, stream>>>(
        x, Wq, Wk, Wv, Wo, xb, wqkv);

    const float qscale = 0.125f * 1.44269504088896340736f;  // 1/sqrt(64) * log2(e)
    gemm_qkv<<<dim3(768), 512, 0, stream>>>(xb, wqkv, qbuf, kbuf, vtb, qscale);

    attn_kernel<<<dim3(Bsz * NH, 32), 256, 0, stream>>>(qbuf, kbuf, vtb, abuf);

    gemm_out<<<dim3(256), 512, 0, stream>>>(abuf, wob, out);
}